// Round 1
// baseline (645.858 us; speedup 1.0000x reference)
//
#include <hip/hip_runtime.h>

typedef unsigned short u16;
typedef unsigned int   u32;
typedef __attribute__((ext_vector_type(4))) float f32x4;
typedef __attribute__((ext_vector_type(8))) short short8;

#define MODEL_DIM 1024
#define SEQ 2048
#define BATCH 4
#define NHEAD 16
#define HDIM 64
#define MTOT (BATCH*SEQ)                       /* 8192 */
#define ELEMS ((size_t)MTOT*MODEL_DIM)         /* 8388608 */

__device__ __forceinline__ u16 f2bf(float f) {
    u32 u = __float_as_uint(f);
    u = (u + 0x7fffu + ((u >> 16) & 1u)) >> 16;   // RNE
    return (u16)u;
}
__device__ __forceinline__ u32 pack2(float a, float b) {
    return (u32)f2bf(a) | ((u32)f2bf(b) << 16);
}

// ---------------------------------------------------------------- cast X -> bf16
__global__ void cast_x_k(const float* __restrict__ X, u16* __restrict__ Xb) {
    size_t i = ((size_t)blockIdx.x * 256 + threadIdx.x) * 4;
    float4 v = *(const float4*)(X + i);
    uint2 o; o.x = pack2(v.x, v.y); o.y = pack2(v.z, v.w);
    *(uint2*)(Xb + i) = o;
}

// ---------------------------------------------- W[k][n] fp32 -> Wt[w][n][k] bf16
__global__ void transw_k(const float* __restrict__ Wq, const float* __restrict__ Wk,
                         const float* __restrict__ Wv, const float* __restrict__ Wo,
                         u16* __restrict__ Wt) {
    __shared__ float tile[32][33];
    int z = blockIdx.z;
    const float* W = (z == 0) ? Wq : (z == 1) ? Wk : (z == 2) ? Wv : Wo;
    int k0 = blockIdx.y * 32, n0 = blockIdx.x * 32;
    int x = threadIdx.x, y = threadIdx.y;               // 32 x 8
    for (int i = 0; i < 4; ++i)
        tile[y + i * 8][x] = W[(size_t)(k0 + y + i * 8) * MODEL_DIM + n0 + x];
    __syncthreads();
    u16* out = Wt + ((size_t)z << 20);
    for (int i = 0; i < 4; ++i)
        out[(size_t)(n0 + y + i * 8) * MODEL_DIM + k0 + x] = f2bf(tile[x][y + i * 8]);
}

// ----------------------------------------------------------------- GEMM 128x128
// MODE 0: A=Xb, N=3072 (Q|K fp32 -> outQK, V bf16 -> outV), bias per region.
// MODE 1: A=Ob, N=1024, fp32 out + bo.
template<int MODE>
__global__ __launch_bounds__(256) void gemm128_k(
        const u16* __restrict__ A, const u16* __restrict__ Wt,
        float* __restrict__ outQK, u16* __restrict__ outV, float* __restrict__ outO,
        const float* __restrict__ bq, const float* __restrict__ bk,
        const float* __restrict__ bv, const float* __restrict__ bo) {
    __shared__ __align__(16) u16 As[128 * 40];
    __shared__ __align__(16) u16 Bs[128 * 40];
    const int tid  = threadIdx.x;
    const int wave = tid >> 6, lane = tid & 63;
    const int l15  = lane & 15, quad = lane >> 4;
    const int wm = (wave & 1) * 64, wn = (wave >> 1) * 64;
    const int m0 = blockIdx.x * 128;
    const int n0 = blockIdx.y * 128;

    const u16* bbase;
    if (MODE == 0) {
        int region = n0 >> 10;
        bbase = Wt + ((size_t)region << 20) + (size_t)(n0 & 1023) * MODEL_DIM;
    } else {
        bbase = Wt + ((size_t)3 << 20) + (size_t)n0 * MODEL_DIM;
    }
    const u16* abase = A + (size_t)m0 * MODEL_DIM;

    f32x4 acc[4][4] = {};
    const int r0 = tid >> 2,         kc0 = (tid & 3) * 8;          // chunks 0..255
    const int r1 = (tid + 256) >> 2, kc1 = kc0;                    // chunks 256..511

    for (int k0 = 0; k0 < MODEL_DIM; k0 += 32) {
        uint4 a0 = *(const uint4*)(abase + (size_t)r0 * MODEL_DIM + k0 + kc0);
        uint4 a1 = *(const uint4*)(abase + (size_t)r1 * MODEL_DIM + k0 + kc1);
        uint4 b0 = *(const uint4*)(bbase + (size_t)r0 * MODEL_DIM + k0 + kc0);
        uint4 b1 = *(const uint4*)(bbase + (size_t)r1 * MODEL_DIM + k0 + kc1);
        *(uint4*)(&As[r0 * 40 + kc0]) = a0;
        *(uint4*)(&As[r1 * 40 + kc1]) = a1;
        *(uint4*)(&Bs[r0 * 40 + kc0]) = b0;
        *(uint4*)(&Bs[r1 * 40 + kc1]) = b1;
        __syncthreads();
        short8 af[4], bf[4];
        for (int i = 0; i < 4; ++i)
            af[i] = *(const short8*)(&As[(wm + i * 16 + l15) * 40 + quad * 8]);
        for (int i = 0; i < 4; ++i)
            bf[i] = *(const short8*)(&Bs[(wn + i * 16 + l15) * 40 + quad * 8]);
        for (int mi = 0; mi < 4; ++mi)
            for (int ni = 0; ni < 4; ++ni)
                acc[mi][ni] = __builtin_amdgcn_mfma_f32_16x16x32_bf16(
                                  af[mi], bf[ni], acc[mi][ni], 0, 0, 0);
        __syncthreads();
    }

    // epilogue: C/D layout col=lane&15, row=quad*4+reg  [m89/m91 verified]
    if (MODE == 0) {
        const int region = n0 >> 10;
        const float* bias = (region == 0) ? bq : (region == 1) ? bk : bv;
        float* qkout = outQK + (region == 1 ? ELEMS : 0);
        for (int mi = 0; mi < 4; ++mi)
            for (int r = 0; r < 4; ++r) {
                size_t rowg = (size_t)(m0 + wm + mi * 16 + quad * 4 + r);
                for (int ni = 0; ni < 4; ++ni) {
                    int col = (n0 + wn + ni * 16 + l15) & 1023;
                    float v = acc[mi][ni][r] + bias[col];
                    if (region < 2) qkout[rowg * MODEL_DIM + col] = v;
                    else            outV [rowg * MODEL_DIM + col] = f2bf(v);
                }
            }
    } else {
        for (int mi = 0; mi < 4; ++mi)
            for (int r = 0; r < 4; ++r) {
                size_t rowg = (size_t)(m0 + wm + mi * 16 + quad * 4 + r);
                for (int ni = 0; ni < 4; ++ni) {
                    int colg = n0 + wn + ni * 16 + l15;
                    outO[rowg * MODEL_DIM + colg] = acc[mi][ni][r] + bo[colg];
                }
            }
    }
}

// -------------------------------------------------- RoPE in-place on fp32 Q & K
__global__ void rope_k(float* __restrict__ QK) {
    int tid = blockIdx.x * 256 + threadIdx.x;     // 0 .. 2*B*S*512-1
    int row = tid >> 9;                            // 0 .. 16383 (Q rows then K rows)
    int i   = tid & 511;                           // pair index
    int s   = row & 2047;                          // sequence position
    float inv = __expf(-(float)i * (9.210340371976184f / 512.0f)); // 10000^(-i/512)
    float ang = (float)s * inv;
    float sn, cs;
    sincosf(ang, &sn, &cs);                        // accurate: ang up to 2047 rad
    float2 v = *(const float2*)(QK + (size_t)row * MODEL_DIM + 2 * i);
    float2 o;
    o.x = v.x * cs - v.y * sn;
    o.y = v.x * sn + v.y * cs;
    *(float2*)(QK + (size_t)row * MODEL_DIM + 2 * i) = o;
}

// ------------------------------------------------------- flash attention (causal)
// grid (S/64, H, B); 256 threads = 4 waves, each wave owns 16 q-rows.
__global__ __launch_bounds__(256) void attn_k(const float* __restrict__ QK,
                                              const u16* __restrict__ V,
                                              u16* __restrict__ O) {
    __shared__ __align__(16) u16 Ks[32 * 64];      // XOR-swizzled 16B chunks
    __shared__ __align__(16) u16 Vt[64 * 40];      // V^T, stride 40 (2-way only)
    __shared__ __align__(16) u16 Pl[4 * 16 * 40];  // per-wave P transpose area
    const int tid  = threadIdx.x;
    const int wave = tid >> 6, lane = tid & 63;
    const int l15  = lane & 15, quad = lane >> 4;
    const int qt = blockIdx.x, h = blockIdx.y, b = blockIdx.z;
    const int q0 = qt * 64;
    const float* Qp = QK;
    const float* Kp = QK + ELEMS;

    // Q fragments (A-operand: m=lane&15, k=quad*8+j), fp32 -> bf16, stay in regs
    short8 aq[2];
    {
        const float* qrow = Qp + (size_t)(b * SEQ + q0 + wave * 16 + l15) * MODEL_DIM
                               + h * HDIM + quad * 8;
        for (int s = 0; s < 2; ++s) {
            float4 v0 = *(const float4*)(qrow + s * 32);
            float4 v1 = *(const float4*)(qrow + s * 32 + 4);
            short8 a;
            a[0] = (short)f2bf(v0.x); a[1] = (short)f2bf(v0.y);
            a[2] = (short)f2bf(v0.z); a[3] = (short)f2bf(v0.w);
            a[4] = (short)f2bf(v1.x); a[5] = (short)f2bf(v1.y);
            a[6] = (short)f2bf(v1.z); a[7] = (short)f2bf(v1.w);
            aq[s] = a;
        }
    }

    float m_i[4], l_i[4];
    f32x4 o_acc[4] = {};
    for (int r = 0; r < 4; ++r) { m_i[r] = -1e30f; l_i[r] = 0.f; }

    const int nkt = (q0 + 64) >> 5;
    for (int kt = 0; kt < nkt; ++kt) {
        const int k0 = kt * 32;
        {   // stage K tile (32 keys x 64 dims), fp32->bf16, chunk-XOR swizzle
            int key = tid >> 3, c = tid & 7;
            const float* kp = Kp + (size_t)(b * SEQ + k0 + key) * MODEL_DIM
                                 + h * HDIM + c * 8;
            float4 v0 = *(const float4*)kp;
            float4 v1 = *(const float4*)(kp + 4);
            uint4 pk;
            pk.x = pack2(v0.x, v0.y); pk.y = pack2(v0.z, v0.w);
            pk.z = pack2(v1.x, v1.y); pk.w = pack2(v1.z, v1.w);
            int sw = c ^ (key & 7);
            *(uint4*)(&Ks[key * 64 + sw * 8]) = pk;
        }
        // stage V^T (dims x keys, stride 40)
        for (int i = 0; i < 4; ++i) {
            int idx = tid + i * 256;               // 0..1023
            int key = idx >> 5, dp = idx & 31;
            const u32* vp = (const u32*)(V + (size_t)(b * SEQ + k0 + key) * MODEL_DIM
                                           + h * HDIM);
            u32 u = vp[dp];
            Vt[(2 * dp) * 40 + key]     = (u16)(u & 0xffff);
            Vt[(2 * dp + 1) * 40 + key] = (u16)(u >> 16);
        }
        __syncthreads();

        // S = Q K^T  (B-operand: n=key=lane&15, k=dim=quad*8+j)
        f32x4 sf[2];
        for (int nt = 0; nt < 2; ++nt) {
            int key = nt * 16 + l15;
            f32x4 sa = {0.f, 0.f, 0.f, 0.f};
            for (int s = 0; s < 2; ++s) {
                int chunk = s * 4 + quad;
                short8 kb = *(const short8*)(&Ks[key * 64 + ((chunk ^ (key & 7)) * 8)]);
                sa = __builtin_amdgcn_mfma_f32_16x16x32_bf16(aq[s], kb, sa, 0, 0, 0);
            }
            sf[nt] = sa;
        }
        // scale + causal mask + row max
        float rmax[4];
        for (int r = 0; r < 4; ++r) {
            int qg = q0 + wave * 16 + quad * 4 + r;
            float v0 = sf[0][r] * 0.125f, v1 = sf[1][r] * 0.125f;
            v0 = (k0 + l15      <= qg) ? v0 : -1e30f;
            v1 = (k0 + 16 + l15 <= qg) ? v1 : -1e30f;
            sf[0][r] = v0; sf[1][r] = v1;
            rmax[r] = fmaxf(v0, v1);
        }
        for (int m = 1; m < 16; m <<= 1)
            for (int r = 0; r < 4; ++r)
                rmax[r] = fmaxf(rmax[r], __shfl_xor(rmax[r], m, 64));
        // online softmax update
        float alpha[4], psum[4];
        for (int r = 0; r < 4; ++r) {
            float mn = fmaxf(m_i[r], rmax[r]);
            alpha[r] = __expf(m_i[r] - mn);
            m_i[r] = mn;
            float p0 = __expf(sf[0][r] - mn);
            float p1 = __expf(sf[1][r] - mn);
            sf[0][r] = p0; sf[1][r] = p1;
            psum[r] = p0 + p1;
        }
        for (int m = 1; m < 16; m <<= 1)
            for (int r = 0; r < 4; ++r)
                psum[r] += __shfl_xor(psum[r], m, 64);
        for (int r = 0; r < 4; ++r) l_i[r] = l_i[r] * alpha[r] + psum[r];
        for (int d = 0; d < 4; ++d) {
            o_acc[d][0] *= alpha[0]; o_acc[d][1] *= alpha[1];
            o_acc[d][2] *= alpha[2]; o_acc[d][3] *= alpha[3];
        }
        // P: C-layout -> A-layout via per-wave LDS round-trip (m120 transform)
        u16* pw = &Pl[wave * 640];
        for (int r = 0; r < 4; ++r) {
            int row = quad * 4 + r;
            pw[row * 40 + l15]      = f2bf(sf[0][r]);
            pw[row * 40 + 16 + l15] = f2bf(sf[1][r]);
        }
        short8 pf = *(const short8*)(&Pl[wave * 640 + l15 * 40 + quad * 8]);
        for (int d = 0; d < 4; ++d) {
            short8 vb = *(const short8*)(&Vt[(d * 16 + l15) * 40 + quad * 8]);
            o_acc[d] = __builtin_amdgcn_mfma_f32_16x16x32_bf16(pf, vb, o_acc[d], 0, 0, 0);
        }
        __syncthreads();
    }

    // normalize + write O (bf16)
    for (int d = 0; d < 4; ++d)
        for (int r = 0; r < 4; ++r) {
            float val = o_acc[d][r] / l_i[r];
            size_t orow = (size_t)(b * SEQ + q0 + wave * 16 + quad * 4 + r);
            O[orow * MODEL_DIM + h * HDIM + d * 16 + l15] = f2bf(val);
        }
}

// --------------------------------------------------------------------- launcher
extern "C" void kernel_launch(void* const* d_in, const int* in_sizes, int n_in,
                              void* d_out, int out_size, void* d_ws, size_t ws_size,
                              hipStream_t stream) {
    const float* X  = (const float*)d_in[0];
    const float* Wq = (const float*)d_in[1];
    const float* bq = (const float*)d_in[2];
    const float* Wk = (const float*)d_in[3];
    const float* bk = (const float*)d_in[4];
    const float* Wv = (const float*)d_in[5];
    const float* bv = (const float*)d_in[6];
    const float* Wo = (const float*)d_in[7];
    const float* bo = (const float*)d_in[8];
    float* out = (float*)d_out;

    // ws layout (bytes): [Xb/Ob 16.7M][Wt 8.4M][QKf 67.1M][Vb 16.7M] = 104 MB
    char* ws = (char*)d_ws;
    u16*   Xb  = (u16*)ws;                       // aliased by Ob after QKV GEMM
    u16*   Ob  = (u16*)ws;
    u16*   Wt  = (u16*)(ws + 16777216);
    float* QKf = (float*)(ws + 25165824);
    u16*   Vb  = (u16*)(ws + 92274688);

    cast_x_k<<<dim3(ELEMS / 1024), dim3(256), 0, stream>>>(X, Xb);
    transw_k<<<dim3(32, 32, 4), dim3(32, 8), 0, stream>>>(Wq, Wk, Wv, Wo, Wt);
    gemm128_k<0><<<dim3(64, 24), dim3(256), 0, stream>>>(Xb, Wt, QKf, Vb, nullptr,
                                                         bq, bk, bv, nullptr);
    rope_k<<<dim3(ELEMS / 256), dim3(256), 0, stream>>>(QKf);
    attn_k<<<dim3(SEQ / 64, NHEAD, BATCH), dim3(256), 0, stream>>>(QKf, Vb, Ob);
    gemm128_k<1><<<dim3(64, 8), dim3(256), 0, stream>>>(Ob, Wt, nullptr, nullptr, out,
                                                        nullptr, nullptr, nullptr, bo);
}

// Round 2
// 376.530 us; speedup vs baseline: 1.7153x; 1.7153x over previous
//
#include <hip/hip_runtime.h>

typedef unsigned short u16;
typedef unsigned int   u32;
typedef __attribute__((ext_vector_type(4))) float f32x4;
typedef __attribute__((ext_vector_type(8))) short short8;

#define MODEL_DIM 1024
#define SEQ 2048
#define BATCH 4
#define NHEAD 16
#define HDIM 64
#define MTOT (BATCH*SEQ)                       /* 8192 */
#define ELEMS ((size_t)MTOT*MODEL_DIM)         /* 8388608 */

__device__ __forceinline__ u16 f2bf(float f) {
    u32 u = __float_as_uint(f);
    u = (u + 0x7fffu + ((u >> 16) & 1u)) >> 16;   // RNE
    return (u16)u;
}
__device__ __forceinline__ u32 pack2(float a, float b) {
    return (u32)f2bf(a) | ((u32)f2bf(b) << 16);
}
__device__ __forceinline__ float bflo(u32 u) { return __uint_as_float(u << 16); }
__device__ __forceinline__ float bfhi(u32 u) { return __uint_as_float(u & 0xffff0000u); }

// ---------------------------------------------------------------- cast X -> bf16
__global__ void cast_x_k(const float* __restrict__ X, u16* __restrict__ Xb) {
    size_t i = ((size_t)blockIdx.x * 256 + threadIdx.x) * 4;
    float4 v = *(const float4*)(X + i);
    uint2 o; o.x = pack2(v.x, v.y); o.y = pack2(v.z, v.w);
    *(uint2*)(Xb + i) = o;
}

// ---------------------------------------------- W[k][n] fp32 -> Wt[w][n][k] bf16
__global__ void transw_k(const float* __restrict__ Wq, const float* __restrict__ Wk,
                         const float* __restrict__ Wv, const float* __restrict__ Wo,
                         u16* __restrict__ Wt) {
    __shared__ float tile[32][33];
    int z = blockIdx.z;
    const float* W = (z == 0) ? Wq : (z == 1) ? Wk : (z == 2) ? Wv : Wo;
    int k0 = blockIdx.y * 32, n0 = blockIdx.x * 32;
    int x = threadIdx.x, y = threadIdx.y;               // 32 x 8
    for (int i = 0; i < 4; ++i)
        tile[y + i * 8][x] = W[(size_t)(k0 + y + i * 8) * MODEL_DIM + n0 + x];
    __syncthreads();
    u16* out = Wt + ((size_t)z << 20);
    for (int i = 0; i < 4; ++i)
        out[(size_t)(n0 + y + i * 8) * MODEL_DIM + k0 + x] = f2bf(tile[x][y + i * 8]);
}

// ----------------------------------------------------------------- GEMM 128x128
// MODE 0: A=Xb, N=3072: writes Qb,Kb,Vb (bf16, +bias).
// MODE 1: A=Ob, N=1024: writes fp32 out + bo.
template<int MODE>
__global__ __launch_bounds__(256) void gemm128_k(
        const u16* __restrict__ A, const u16* __restrict__ Wt,
        u16* __restrict__ Qb, u16* __restrict__ Kb, u16* __restrict__ Vb,
        float* __restrict__ outO,
        const float* __restrict__ bq, const float* __restrict__ bk,
        const float* __restrict__ bv, const float* __restrict__ bo) {
    __shared__ __align__(16) u16 As[128 * 40];
    __shared__ __align__(16) u16 Bs[128 * 40];
    const int tid  = threadIdx.x;
    const int wave = tid >> 6, lane = tid & 63;
    const int l15  = lane & 15, quad = lane >> 4;
    const int wm = (wave & 1) * 64, wn = (wave >> 1) * 64;
    const int m0 = blockIdx.x * 128;
    const int n0 = blockIdx.y * 128;

    const u16* bbase;
    if (MODE == 0) {
        int region = n0 >> 10;
        bbase = Wt + ((size_t)region << 20) + (size_t)(n0 & 1023) * MODEL_DIM;
    } else {
        bbase = Wt + ((size_t)3 << 20) + (size_t)n0 * MODEL_DIM;
    }
    const u16* abase = A + (size_t)m0 * MODEL_DIM;

    f32x4 acc[4][4] = {};
    const int r0 = tid >> 2,         kc0 = (tid & 3) * 8;
    const int r1 = (tid + 256) >> 2, kc1 = kc0;

    for (int k0 = 0; k0 < MODEL_DIM; k0 += 32) {
        uint4 a0 = *(const uint4*)(abase + (size_t)r0 * MODEL_DIM + k0 + kc0);
        uint4 a1 = *(const uint4*)(abase + (size_t)r1 * MODEL_DIM + k0 + kc1);
        uint4 b0 = *(const uint4*)(bbase + (size_t)r0 * MODEL_DIM + k0 + kc0);
        uint4 b1 = *(const uint4*)(bbase + (size_t)r1 * MODEL_DIM + k0 + kc1);
        *(uint4*)(&As[r0 * 40 + kc0]) = a0;
        *(uint4*)(&As[r1 * 40 + kc1]) = a1;
        *(uint4*)(&Bs[r0 * 40 + kc0]) = b0;
        *(uint4*)(&Bs[r1 * 40 + kc1]) = b1;
        __syncthreads();
        short8 af[4], bf[4];
        for (int i = 0; i < 4; ++i)
            af[i] = *(const short8*)(&As[(wm + i * 16 + l15) * 40 + quad * 8]);
        for (int i = 0; i < 4; ++i)
            bf[i] = *(const short8*)(&Bs[(wn + i * 16 + l15) * 40 + quad * 8]);
        for (int mi = 0; mi < 4; ++mi)
            for (int ni = 0; ni < 4; ++ni)
                acc[mi][ni] = __builtin_amdgcn_mfma_f32_16x16x32_bf16(
                                  af[mi], bf[ni], acc[mi][ni], 0, 0, 0);
        __syncthreads();
    }

    // epilogue: C/D layout col=lane&15, row=quad*4+reg
    if (MODE == 0) {
        const int region = n0 >> 10;
        const float* bias = (region == 0) ? bq : (region == 1) ? bk : bv;
        u16* dst = (region == 0) ? Qb : (region == 1) ? Kb : Vb;
        for (int mi = 0; mi < 4; ++mi)
            for (int r = 0; r < 4; ++r) {
                size_t rowg = (size_t)(m0 + wm + mi * 16 + quad * 4 + r);
                for (int ni = 0; ni < 4; ++ni) {
                    int col = (n0 + wn + ni * 16 + l15) & 1023;
                    dst[rowg * MODEL_DIM + col] = f2bf(acc[mi][ni][r] + bias[col]);
                }
            }
    } else {
        for (int mi = 0; mi < 4; ++mi)
            for (int r = 0; r < 4; ++r) {
                size_t rowg = (size_t)(m0 + wm + mi * 16 + quad * 4 + r);
                for (int ni = 0; ni < 4; ++ni) {
                    int colg = n0 + wn + ni * 16 + l15;
                    outO[rowg * MODEL_DIM + colg] = acc[mi][ni][r] + bo[colg];
                }
            }
    }
}

// ------------------------------------ RoPE in-place on bf16 Q|K (contiguous bufs)
// rows 0..8191 = Q (also folds in softmax scale 0.125), rows 8192..16383 = K.
__global__ void rope_k(u16* __restrict__ QK) {
    int gtid = blockIdx.x * 256 + threadIdx.x;
    int row = gtid >> 8;                 // 0..16383
    int i   = gtid & 255;                // uint2 index within row (dims 4i..4i+3)
    int s   = row & 2047;
    float p0 = (float)(2 * i), p1 = (float)(2 * i + 1);
    const float c = -0.017989922f;       // -ln(10000)/512
    float inv0 = __expf(p0 * c), inv1 = __expf(p1 * c);
    float sn0, cs0, sn1, cs1;
    __sincosf((float)s * inv0, &sn0, &cs0);
    __sincosf((float)s * inv1, &sn1, &cs1);
    u16* ptr = QK + (size_t)row * MODEL_DIM + 4 * i;
    uint2 u = *(const uint2*)ptr;
    float v0 = bflo(u.x), v1 = bfhi(u.x), v2 = bflo(u.y), v3 = bfhi(u.y);
    float r0 = v0 * cs0 - v1 * sn0;
    float r1 = v0 * sn0 + v1 * cs0;
    float r2 = v2 * cs1 - v3 * sn1;
    float r3 = v2 * sn1 + v3 * cs1;
    float sc = (row < MTOT) ? 0.125f : 1.0f;   // 1/sqrt(64) folded into Q (exact)
    uint2 o; o.x = pack2(r0 * sc, r1 * sc); o.y = pack2(r2 * sc, r3 * sc);
    *(uint2*)ptr = o;
}

// ---------------------------- V [b*S][h*64+d] bf16  ->  VT32[(bh*64+d)][s-pairs]
__global__ __launch_bounds__(256) void vt_k(const u32* __restrict__ Vb32,
                                            u32* __restrict__ VT32) {
    __shared__ u32 tile[64 * 33];
    int bh = blockIdx.y, b = bh >> 4, h = bh & 15;
    int s0 = blockIdx.x * 64;
    int t = threadIdx.x;
    for (int it = 0; it < 8; ++it) {
        int idx = it * 256 + t;
        int s = idx >> 5, dc = idx & 31;     // dc: u32 = 2 dims
        tile[s * 33 + dc] = Vb32[(size_t)(b * SEQ + s0 + s) * (MODEL_DIM / 2)
                                 + h * (HDIM / 2) + dc];
    }
    __syncthreads();
    for (int it = 0; it < 8; ++it) {
        int idx = it * 256 + t;
        int d = idx >> 5, sc = idx & 31;     // sc: u32 = 2 seq positions
        u32 w0 = tile[(2 * sc) * 33 + (d >> 1)];
        u32 w1 = tile[(2 * sc + 1) * 33 + (d >> 1)];
        u32 val = (d & 1) ? ((w0 >> 16) | (w1 & 0xffff0000u))
                          : ((w0 & 0xffffu) | (w1 << 16));
        VT32[(size_t)(bh * HDIM + d) * (SEQ / 2) + (s0 >> 1) + sc] = val;
    }
}

// ------------------------------------------------------- flash attention (causal)
// grid (16,16,4) = (qt reversed, h, b); 256 thr = 4 waves; wave owns 32 q-rows.
// Computes S^T = K Q^T (C-layout: q=lane&15, key=quad*4+r) and O^T = V^T P^T.
__global__ __launch_bounds__(256, 4) void attn_k(const u16* __restrict__ Qb,
                                                 const u16* __restrict__ Kb,
                                                 const u32* __restrict__ VT32,
                                                 u16* __restrict__ Ob) {
    __shared__ __align__(16) u16 Ks[64 * 64];      // [key][dim], chunk-XOR swizzle
    __shared__ __align__(16) u16 Vs[64 * 64];      // [d][key],   chunk-XOR swizzle
    __shared__ __align__(16) u16 Pl[4 * 32 * 72];  // per-wave P^T [q][key], pad 8
    const int tid  = threadIdx.x;
    const int wave = tid >> 6, lane = tid & 63;
    const int l15  = lane & 15, quad = lane >> 4;
    const int qt = 15 - blockIdx.x;                // heavy blocks first
    const int h = blockIdx.y, b = blockIdx.z;
    const int q0 = qt * 128;
    const int qbase = q0 + wave * 32;
    u16* pw = &Pl[wave * 32 * 72];

    // Q B-frags (n=q=lane&15, k=dim=quad*8+j), already scaled by 0.125 in rope
    short8 qfr[2][2];
    for (int qf = 0; qf < 2; ++qf)
        for (int ks = 0; ks < 2; ++ks)
            qfr[qf][ks] = *(const short8*)(Qb
                + (size_t)(b * SEQ + qbase + qf * 16 + l15) * MODEL_DIM
                + h * HDIM + ks * 32 + quad * 8);

    float m_i[2] = {-1e30f, -1e30f}, l_i[2] = {0.f, 0.f};
    f32x4 o_acc[4][2] = {};                        // [dt][qf]

    const int nkt = (q0 + 128) >> 6;
    for (int kt = 0; kt < nkt; ++kt) {
        const int k0 = kt * 64;
        for (int it = 0; it < 2; ++it) {           // stage K tile 64x64
            int idx = tid + it * 256;
            int key = idx >> 3, c = idx & 7;
            uint4 v = *(const uint4*)(Kb + (size_t)(b * SEQ + k0 + key) * MODEL_DIM
                                         + h * HDIM + c * 8);
            *(uint4*)(&Ks[key * 64 + ((c ^ (key & 7)) * 8)]) = v;
        }
        for (int it = 0; it < 2; ++it) {           // stage V^T tile 64x64
            int idx = tid + it * 256;
            int d = idx >> 3, c = idx & 7;
            uint4 v = *(const uint4*)(VT32
                + (size_t)((b * NHEAD + h) * HDIM + d) * (SEQ / 2) + (k0 >> 1) + c * 4);
            *(uint4*)(&Vs[d * 64 + ((c ^ (d & 7)) * 8)]) = v;
        }
        __syncthreads();

        if (k0 <= qbase + 31) {                    // wave has live rows this tile
            // S^T = K Q^T
            f32x4 s[4][2] = {};
            for (int ks = 0; ks < 2; ++ks) {
                short8 kfr[4];
                for (int kf = 0; kf < 4; ++kf)
                    kfr[kf] = *(const short8*)(&Ks[(kf * 16 + l15) * 64
                                  + (((ks * 4 + quad) ^ (l15 & 7)) * 8)]);
                for (int kf = 0; kf < 4; ++kf)
                    for (int qf = 0; qf < 2; ++qf)
                        s[kf][qf] = __builtin_amdgcn_mfma_f32_16x16x32_bf16(
                                        kfr[kf], qfr[qf][ks], s[kf][qf], 0, 0, 0);
            }
            for (int qf = 0; qf < 2; ++qf) {
                int qg = qbase + qf * 16 + l15;
                if (k0 + 63 > qbase + qf * 16) {   // diagonal tile: apply mask
                    for (int kf = 0; kf < 4; ++kf)
                        for (int r = 0; r < 4; ++r)
                            if (k0 + kf * 16 + quad * 4 + r > qg)
                                s[kf][qf][r] = -1e30f;
                }
                float rmax = s[0][qf][0];
                for (int kf = 0; kf < 4; ++kf)
                    for (int r = 0; r < 4; ++r) rmax = fmaxf(rmax, s[kf][qf][r]);
                rmax = fmaxf(rmax, __shfl_xor(rmax, 16, 64));
                rmax = fmaxf(rmax, __shfl_xor(rmax, 32, 64));
                float mn = fmaxf(m_i[qf], rmax);
                float alpha = __expf(m_i[qf] - mn);
                m_i[qf] = mn;
                float psum = 0.f;
                for (int kf = 0; kf < 4; ++kf)
                    for (int r = 0; r < 4; ++r) {
                        float p = __expf(s[kf][qf][r] - mn);
                        s[kf][qf][r] = p;
                        psum += p;
                    }
                psum += __shfl_xor(psum, 16, 64);
                psum += __shfl_xor(psum, 32, 64);
                l_i[qf] = l_i[qf] * alpha + psum;
                for (int dt = 0; dt < 4; ++dt)
                    for (int r = 0; r < 4; ++r) o_acc[dt][qf][r] *= alpha;
                for (int kf = 0; kf < 4; ++kf) {   // P^T -> LDS (uint2, ~2-way)
                    uint2 w;
                    w.x = pack2(s[kf][qf][0], s[kf][qf][1]);
                    w.y = pack2(s[kf][qf][2], s[kf][qf][3]);
                    *(uint2*)(&pw[(qf * 16 + l15) * 72 + kf * 16 + quad * 4]) = w;
                }
            }
            // O^T += V^T P^T
            for (int ks = 0; ks < 2; ++ks) {
                short8 pfr[2], vfr[4];
                for (int qf = 0; qf < 2; ++qf)
                    pfr[qf] = *(const short8*)(&pw[(qf * 16 + l15) * 72
                                                   + ks * 32 + quad * 8]);
                for (int dt = 0; dt < 4; ++dt)
                    vfr[dt] = *(const short8*)(&Vs[(dt * 16 + l15) * 64
                                  + (((ks * 4 + quad) ^ (l15 & 7)) * 8)]);
                for (int dt = 0; dt < 4; ++dt)
                    for (int qf = 0; qf < 2; ++qf)
                        o_acc[dt][qf] = __builtin_amdgcn_mfma_f32_16x16x32_bf16(
                                            vfr[dt], pfr[qf], o_acc[dt][qf], 0, 0, 0);
            }
        }
        __syncthreads();
    }

    // O^T C-layout: q = lane&15, d = quad*4+r (within dt)
    for (int qf = 0; qf < 2; ++qf) {
        float rl = 1.f / l_i[qf];
        int q = qbase + qf * 16 + l15;
        for (int dt = 0; dt < 4; ++dt) {
            uint2 w;
            w.x = pack2(o_acc[dt][qf][0] * rl, o_acc[dt][qf][1] * rl);
            w.y = pack2(o_acc[dt][qf][2] * rl, o_acc[dt][qf][3] * rl);
            *(uint2*)(&Ob[(size_t)(b * SEQ + q) * MODEL_DIM
                          + h * HDIM + dt * 16 + quad * 4]) = w;
        }
    }
}

// --------------------------------------------------------------------- launcher
extern "C" void kernel_launch(void* const* d_in, const int* in_sizes, int n_in,
                              void* d_out, int out_size, void* d_ws, size_t ws_size,
                              hipStream_t stream) {
    const float* X  = (const float*)d_in[0];
    const float* Wq = (const float*)d_in[1];
    const float* bq = (const float*)d_in[2];
    const float* Wk = (const float*)d_in[3];
    const float* bk = (const float*)d_in[4];
    const float* Wv = (const float*)d_in[5];
    const float* bv = (const float*)d_in[6];
    const float* Wo = (const float*)d_in[7];
    const float* bo = (const float*)d_in[8];
    float* out = (float*)d_out;

    // ws: [Xb/Ob 16.78M][Wt 8.39M][Qb 16.78M][Kb 16.78M][Vb 16.78M][VT 16.78M]=92.3M
    char* ws = (char*)d_ws;
    u16* Xb   = (u16*)ws;                       // aliased by Ob after QKV GEMM
    u16* Ob   = (u16*)ws;
    u16* Wt   = (u16*)(ws + 16777216);
    u16* Qb   = (u16*)(ws + 25165824);
    u16* Kb   = (u16*)(ws + 41943040);          // contiguous after Qb (rope relies)
    u16* Vb   = (u16*)(ws + 58720256);
    u32* VT32 = (u32*)(ws + 75497472);

    cast_x_k<<<dim3(ELEMS / 1024), dim3(256), 0, stream>>>(X, Xb);
    transw_k<<<dim3(32, 32, 4), dim3(32, 8), 0, stream>>>(Wq, Wk, Wv, Wo, Wt);
    gemm128_k<0><<<dim3(64, 24), dim3(256), 0, stream>>>(Xb, Wt, Qb, Kb, Vb, nullptr,
                                                         bq, bk, bv, nullptr);
    rope_k<<<dim3(16384), dim3(256), 0, stream>>>(Qb);          // covers Qb+Kb
    vt_k<<<dim3(32, 64), dim3(256), 0, stream>>>((const u32*)Vb, VT32);
    attn_k<<<dim3(16, 16, 4), dim3(256), 0, stream>>>(Qb, Kb, VT32, Ob);
    gemm128_k<1><<<dim3(64, 8), dim3(256), 0, stream>>>(Ob, Wt, nullptr, nullptr,
                                                        nullptr, out,
                                                        nullptr, nullptr, nullptr, bo);
}